// Round 15
// baseline (333.405 us; speedup 1.0000x reference)
//
#include <hip/hip_runtime.h>
#include <hip/hip_bf16.h>
#include <float.h>
#include <math.h>

#define N_NODES 50000
#define N_EDGES 400000
#define ETOT    (N_EDGES + N_NODES)   // 450000
#define F_IN    5
#define HEADS   8
#define C1      64
#define C2      32
#define C3      16
#define HC1     (HEADS * C1)          // 512
#define HC2     (HEADS * C2)          // 256
#define NEG_SLOPE 0.2f
#define NCHUNK  ((N_NODES + 255) / 256)  // 196
#define NH8     (N_NODES * HEADS)        // 400000
#define MPAD    (((N_NODES + 63) / 64) * 64)  // 50048 rows for MFMA GEMM
#define GCOLS   (HC2 + 16)            // 272: 256 h2 cols + 8 es + 8 ed
#define PACKBLK ((GCOLS * HC1) / 256) // 544 blocks for packW2X part
#define SCATBLK ((ETOT + 255) / 256)  // 1758 blocks for scatter part
#define ES1BLK  ((NH8 + 255) / 256)   // 1563 blocks for es1 part

typedef short bf16x8 __attribute__((ext_vector_type(8)));
typedef float f32x4  __attribute__((ext_vector_type(4)));
typedef unsigned short ushort_t;
typedef unsigned short ushort8_t __attribute__((ext_vector_type(8)));

__device__ __forceinline__ float eluf(float x) {
    return x > 0.f ? x : (expf(x) - 1.f);
}
__device__ __forceinline__ float bf2f(unsigned short u) {
    union { unsigned int i; float f; } v; v.i = ((unsigned int)u) << 16; return v.f;
}
__device__ __forceinline__ float bflo(unsigned int u) {
    union { unsigned int i; float f; } v; v.i = u << 16; return v.f;
}
__device__ __forceinline__ float bfhi(unsigned int u) {
    union { unsigned int i; float f; } v; v.i = u & 0xffff0000u; return v.f;
}
__device__ __forceinline__ unsigned short f2bf(float f) {
    __hip_bfloat16 b = __float2bfloat16(f);
    return *(unsigned short*)&b;
}
__device__ __forceinline__ float softnum(float es, float ed) {
    float v = es + ed;
    v = v > 0.f ? v : NEG_SLOPE * v;
    return expf(v);
}

// ---------------- degree histogram (int count + weighted for GCN) ------
__global__ void k_deg(const int* __restrict__ ei, const float* __restrict__ ew,
                      int* degi, float* degf) {
    int i = blockIdx.x * blockDim.x + threadIdx.x;
    if (i >= ETOT) return;
    int d   = (i < N_EDGES) ? ei[N_EDGES + i] : (i - N_EDGES);
    float w = (i < N_EDGES) ? ew[i] : 1.f;
    atomicAdd(&degi[d], 1);
    atomicAdd(&degf[d], w);
}

// ---------------- 3-kernel exclusive scan over deg[N] ------------------
__global__ void k_scan_a(const int* __restrict__ deg, int* __restrict__ part) {
    __shared__ int lds[256];
    int t = threadIdx.x;
    int i = blockIdx.x * 256 + t;
    lds[t] = (i < N_NODES) ? deg[i] : 0;
    __syncthreads();
    for (int off = 128; off >= 1; off >>= 1) {
        if (t < off) lds[t] += lds[t + off];
        __syncthreads();
    }
    if (t == 0) part[blockIdx.x] = lds[0];
}

__global__ void k_scan_b(int* part) {
    __shared__ int lds[256];
    int t = threadIdx.x;
    int v = (t < NCHUNK) ? part[t] : 0;
    lds[t] = v;
    __syncthreads();
    for (int off = 1; off < 256; off <<= 1) {
        int x = (t >= off) ? lds[t - off] : 0;
        __syncthreads();
        lds[t] += x;
        __syncthreads();
    }
    if (t < NCHUNK) part[t] = lds[t] - v;
}

__global__ void k_scan_c(const int* __restrict__ deg, const int* __restrict__ part,
                         int* __restrict__ offs) {
    __shared__ int lds[256];
    int t = threadIdx.x;
    int i = blockIdx.x * 256 + t;
    int v = (i < N_NODES) ? deg[i] : 0;
    lds[t] = v;
    __syncthreads();
    for (int off = 1; off < 256; off <<= 1) {
        int x = (t >= off) ? lds[t - off] : 0;
        __syncthreads();
        lds[t] += x;
        __syncthreads();
    }
    int excl = part[blockIdx.x] + lds[t] - v;
    if (i < N_NODES) offs[i] = excl;
    if (i == N_NODES - 1) offs[N_NODES] = excl + v;
}

// -------- merged weight prep: packW2X (blocks 0..543) + fold (block 544)
__global__ void k_prep(const float* __restrict__ W2,
                       const float* __restrict__ a_src2, const float* __restrict__ a_dst2,
                       ushort_t* __restrict__ W2X,
                       const float* __restrict__ W1,
                       const float* __restrict__ a_src1, const float* __restrict__ a_dst1,
                       float* __restrict__ as1f, float* __restrict__ ad1f) {
    if (blockIdx.x < PACKBLK) {
        int idx = blockIdx.x * 256 + threadIdx.x;
        int c = idx >> 9;       // output column 0..271
        int k = idx & 511;      // k index
        float v;
        if (c < HC2) {
            v = W2[(size_t)k * HC2 + c];
        } else {
            int h = (c - HC2) & 7;
            const float* av = (c < HC2 + 8) ? a_src2 : a_dst2;
            v = 0.f;
#pragma unroll 8
            for (int j = 0; j < C2; j++)
                v += W2[(size_t)k * HC2 + h * C2 + j] * av[h * C2 + j];
        }
        W2X[idx] = f2bf(v);
    } else {
        int idx = threadIdx.x;
        if (idx >= HEADS * F_IN) return;
        int h = idx / F_IN, f = idx % F_IN;
        float s = 0.f, d = 0.f;
        for (int c = 0; c < C1; c++) {
            float w = W1[f * HC1 + h * C1 + c];
            s += w * a_src1[h * C1 + c];
            d += w * a_dst1[h * C1 + c];
        }
        as1f[idx] = s;
        ad1f[idx] = d;
    }
}

// -------- merged: scatter CSR (blocks 0..1757) + es1/ed1 (rest) --------
__global__ void k_scatter_es1(const int* __restrict__ ei, const int* __restrict__ offs,
                              int* cursor, int2* __restrict__ csr,
                              const float* __restrict__ x,
                              const float* __restrict__ as1f, const float* __restrict__ ad1f,
                              float* __restrict__ es, float* __restrict__ ed) {
    if (blockIdx.x < SCATBLK) {
        int i = blockIdx.x * 256 + threadIdx.x;
        if (i >= ETOT) return;
        int s, d;
        if (i < N_EDGES) { s = ei[i]; d = ei[N_EDGES + i]; }
        else             { s = d = i - N_EDGES; }
        int pos = offs[d] + atomicAdd(&cursor[d], 1);
        csr[pos] = make_int2(s, i);
    } else {
        int g = (blockIdx.x - SCATBLK) * 256 + threadIdx.x;
        if (g >= NH8) return;
        int n = g >> 3, h = g & 7;
        float vs = 0.f, vd = 0.f;
#pragma unroll
        for (int f = 0; f < F_IN; f++) {
            float xv = x[n * F_IN + f];
            vs += xv * as1f[h * F_IN + f];
            vd += xv * ad1f[h * F_IN + f];
        }
        es[g] = vs;
        ed[g] = vd;
    }
}

// -------- layer-1 aggregation, exp inline, csr software-pipelined ------
__global__ void k_agg_x(const float* __restrict__ x,
                        const float* __restrict__ es1, const float* __restrict__ ed1,
                        const int* __restrict__ offs, const int2* __restrict__ csr,
                        float* __restrict__ aggx) {
    int g = blockIdx.x * blockDim.x + threadIdx.x;
    if (g >= NH8) return;
    int d = g >> 3, h = g & 7;
    float edv = ed1[g];
    int k0 = offs[d], k1 = offs[d + 1];
    float a0 = 0.f, a1 = 0.f, a2 = 0.f, a3 = 0.f, a4 = 0.f, exsum = 0.f;
    int k = k0;
    if (k + 1 < k1) {
        int2 c0 = csr[k], c1 = csr[k + 1];
        for (; k + 3 < k1; k += 2) {
            int2 n0 = csr[k + 2], n1 = csr[k + 3];   // prefetch next pair
            float x0 = softnum(es1[c0.x * HEADS + h], edv);
            float x1 = softnum(es1[c1.x * HEADS + h], edv);
            const float* xp0 = x + c0.x * F_IN;
            const float* xp1 = x + c1.x * F_IN;
            a0 += x0 * xp0[0] + x1 * xp1[0];
            a1 += x0 * xp0[1] + x1 * xp1[1];
            a2 += x0 * xp0[2] + x1 * xp1[2];
            a3 += x0 * xp0[3] + x1 * xp1[3];
            a4 += x0 * xp0[4] + x1 * xp1[4];
            exsum += x0 + x1;
            c0 = n0; c1 = n1;
        }
        {
            float x0 = softnum(es1[c0.x * HEADS + h], edv);
            float x1 = softnum(es1[c1.x * HEADS + h], edv);
            const float* xp0 = x + c0.x * F_IN;
            const float* xp1 = x + c1.x * F_IN;
            a0 += x0 * xp0[0] + x1 * xp1[0];
            a1 += x0 * xp0[1] + x1 * xp1[1];
            a2 += x0 * xp0[2] + x1 * xp1[2];
            a3 += x0 * xp0[3] + x1 * xp1[3];
            a4 += x0 * xp0[4] + x1 * xp1[4];
            exsum += x0 + x1;
            k += 2;
        }
    }
    if (k < k1) {
        int2 c0 = csr[k];
        float x0 = softnum(es1[c0.x * HEADS + h], edv);
        const float* xp0 = x + c0.x * F_IN;
        a0 += x0 * xp0[0];
        a1 += x0 * xp0[1];
        a2 += x0 * xp0[2];
        a3 += x0 * xp0[3];
        a4 += x0 * xp0[4];
        exsum += x0;
    }
    float inv = 1.f / (exsum + 1e-16f);
    aggx[0 * NH8 + g] = a0 * inv;
    aggx[1 * NH8 + g] = a1 * inv;
    aggx[2 * NH8 + g] = a2 * inv;
    aggx[3 * NH8 + g] = a3 * inv;
    aggx[4 * NH8 + g] = a4 * inv;
}

// -------- expand aggx (N,8,5) @ W1 -> x2 = elu(. + b1), store bf16 -----
// One wave per node: lane j owns channels [j*8, j*8+8). No cross-lane ops.
__global__ __launch_bounds__(256) void k_expand(const float* __restrict__ aggx,
                                                const float* __restrict__ W1,
                                                const float* __restrict__ b1,
                                                ushort_t* __restrict__ x2bf) {
    int wave = threadIdx.x >> 6;          // 0..3
    int j    = threadIdx.x & 63;
    int n    = blockIdx.x * 4 + wave;
    if (n >= N_NODES) return;
    int h = j >> 3;                        // head of this channel slice
    int g = n * HEADS + h;
    float av[F_IN];
#pragma unroll
    for (int f = 0; f < F_IN; f++) av[f] = aggx[f * NH8 + g];

    const float* w1p = W1 + j * 8;         // hc = j*8 = h*64 + (j&7)*8
    float4 s0 = *(const float4*)(b1 + j * 8);
    float4 s1 = *(const float4*)(b1 + j * 8 + 4);
#pragma unroll
    for (int f = 0; f < F_IN; f++) {
        float4 w0  = *(const float4*)(w1p + f * HC1);
        float4 w1v = *(const float4*)(w1p + f * HC1 + 4);
        s0.x += av[f] * w0.x;  s0.y += av[f] * w0.y;
        s0.z += av[f] * w0.z;  s0.w += av[f] * w0.w;
        s1.x += av[f] * w1v.x; s1.y += av[f] * w1v.y;
        s1.z += av[f] * w1v.z; s1.w += av[f] * w1v.w;
    }
    ushort8_t o;
    o[0] = f2bf(eluf(s0.x)); o[1] = f2bf(eluf(s0.y));
    o[2] = f2bf(eluf(s0.z)); o[3] = f2bf(eluf(s0.w));
    o[4] = f2bf(eluf(s1.x)); o[5] = f2bf(eluf(s1.y));
    o[6] = f2bf(eluf(s1.z)); o[7] = f2bf(eluf(s1.w));
    *(ushort8_t*)(x2bf + (size_t)n * HC1 + j * 8) = o;
}

// ------ bf16 MFMA GEMM: round-10 version (16 rows/wave, 256 thr) -------
// LDS-staged B + XOR swizzle + reg prefetch. Known-good.
__global__ __launch_bounds__(256, 3) void k_gemm_mfma(const short* __restrict__ A,
                                                      const short* __restrict__ W2X,
                                                      ushort_t* __restrict__ h2bf,
                                                      float* __restrict__ es2,
                                                      float* __restrict__ ed2) {
    __shared__ short Bs[GCOLS * 32];   // 272 cols * 64 B = 17408 B
    int t    = threadIdx.x;
    int wave = t >> 6;
    int lane = t & 63;
    int lo   = lane & 15;
    int quad = lane >> 4;
    int m0   = blockIdx.x * 64 + wave * 16;
    const short* ap = A + (size_t)(m0 + lo) * HC1 + quad * 8;

    f32x4 acc[17];
#pragma unroll
    for (int f = 0; f < 17; f++) acc[f] = (f32x4){0.f, 0.f, 0.f, 0.f};

    // stage tile k0=0
    for (int idx = t; idx < GCOLS * 4; idx += 256) {
        int c = idx >> 2, q = idx & 3;
        int s = (q + c + (c >> 2)) & 3;
        *(bf16x8*)(Bs + c * 32 + s * 8) = *(const bf16x8*)(W2X + (size_t)c * HC1 + q * 8);
    }
    __syncthreads();

#pragma unroll 1
    for (int k0 = 0; k0 < HC1; k0 += 32) {
        int nk = k0 + 32;
        bf16x8 pre[5];
        if (nk < HC1) {
#pragma unroll
            for (int j = 0; j < 5; j++) {
                int idx = t + j * 256;
                if (idx < GCOLS * 4) {
                    int c = idx >> 2, q = idx & 3;
                    pre[j] = *(const bf16x8*)(W2X + (size_t)c * HC1 + nk + q * 8);
                }
            }
        }
        bf16x8 aF = *(const bf16x8*)(ap + k0);
#pragma unroll
        for (int f = 0; f < 17; f++) {
            int c = f * 16 + lo;
            int s = (quad + c + (c >> 2)) & 3;
            bf16x8 bF = *(const bf16x8*)(Bs + c * 32 + s * 8);
            acc[f] = __builtin_amdgcn_mfma_f32_16x16x32_bf16(aF, bF, acc[f], 0, 0, 0);
        }
        __syncthreads();
        if (nk < HC1) {
#pragma unroll
            for (int j = 0; j < 5; j++) {
                int idx = t + j * 256;
                if (idx < GCOLS * 4) {
                    int c = idx >> 2, q = idx & 3;
                    int s = (q + c + (c >> 2)) & 3;
                    *(bf16x8*)(Bs + c * 32 + s * 8) = pre[j];
                }
            }
            __syncthreads();
        }
    }

    int rowb = m0 + quad * 4;
#pragma unroll
    for (int f = 0; f < 16; f++) {
#pragma unroll
        for (int r = 0; r < 4; r++) {
            int row = rowb + r;
            if (row < N_NODES)
                h2bf[(size_t)row * HC2 + f * 16 + lo] = f2bf(acc[f][r]);
        }
    }
#pragma unroll
    for (int r = 0; r < 4; r++) {
        int row = rowb + r;
        if (row < N_NODES) {
            if (lo < 8) es2[row * HEADS + lo]       = acc[16][r];
            else        ed2[row * HEADS + (lo - 8)] = acc[16][r];
        }
    }
}

// -------- layer-2 GAT agg: wave per dst, dual-edge 16B loads -----------
// Lane-half 0 (lanes 0-31) takes even edges, half 1 odd edges; each lane
// loads ushort8 (16 B = 8 channels) of ITS edge -> half the loads, half
// the exp evals vs the 8B/lane version. Trip count (deg+1)/2 is wave-
// uniform (deg>=1 via self-loop); odd-tail lanes clamp csr idx, weight 0.
// Halves merged with 9 wave-uniform shfl_xor(32) at loop end.
__global__ __launch_bounds__(256) void k_gat_agg2(const ushort_t* __restrict__ h2bf,
                                                  const float* __restrict__ es2,
                                                  const float* __restrict__ ed2,
                                                  const int* __restrict__ offs,
                                                  const int2* __restrict__ csr,
                                                  const float* __restrict__ b2,
                                                  ushort_t* __restrict__ x3bf) {
    int wave = threadIdx.x >> 6;
    int lane = threadIdx.x & 63;
    int d = blockIdx.x * 4 + wave;
    if (d >= N_NODES) return;
    int half = lane >> 5;          // 0: even edges, 1: odd edges
    int jc   = lane & 31;          // channel-chunk index: channels [jc*8, jc*8+8)
    int head = jc >> 2;            // head = (jc*8)/32
    float edv = ed2[d * HEADS + head];
    int k0 = offs[d], k1 = offs[d + 1];
    int last  = k1 - 1;
    int iters = (k1 - k0 + 1) >> 1;
    float acc[8];
#pragma unroll
    for (int c = 0; c < 8; c++) acc[c] = 0.f;
    float exsum = 0.f;

    int idx = k0 + half;
    int2 e = csr[min(idx, last)];
    for (int i = 0; i < iters; i++) {
        int nidx = idx + 2;
        int2 en;
        if (i + 1 < iters) en = csr[min(nidx, last)];
        float w = (idx <= last) ? softnum(es2[e.x * HEADS + head], edv) : 0.f;
        uint4 v = *(const uint4*)(h2bf + (size_t)e.x * HC2 + jc * 8);
        acc[0] += w * bflo(v.x);  acc[1] += w * bfhi(v.x);
        acc[2] += w * bflo(v.y);  acc[3] += w * bfhi(v.y);
        acc[4] += w * bflo(v.z);  acc[5] += w * bfhi(v.z);
        acc[6] += w * bflo(v.w);  acc[7] += w * bfhi(v.w);
        exsum += w;
        idx = nidx;
        if (i + 1 < iters) e = en;
    }
    // merge the two edge-parity halves (wave-uniform control flow)
#pragma unroll
    for (int c = 0; c < 8; c++) acc[c] += __shfl_xor(acc[c], 32, 64);
    exsum += __shfl_xor(exsum, 32, 64);

    if (half == 0) {
        float inv = 1.f / (exsum + 1e-16f);
        float4 b0 = *(const float4*)(b2 + jc * 8);
        float4 b1v = *(const float4*)(b2 + jc * 8 + 4);
        ushort8_t o;
        o[0] = f2bf(eluf(acc[0] * inv + b0.x));
        o[1] = f2bf(eluf(acc[1] * inv + b0.y));
        o[2] = f2bf(eluf(acc[2] * inv + b0.z));
        o[3] = f2bf(eluf(acc[3] * inv + b0.w));
        o[4] = f2bf(eluf(acc[4] * inv + b1v.x));
        o[5] = f2bf(eluf(acc[5] * inv + b1v.y));
        o[6] = f2bf(eluf(acc[6] * inv + b1v.z));
        o[7] = f2bf(eluf(acc[7] * inv + b1v.w));
        *(ushort8_t*)(x3bf + (size_t)d * HC2 + jc * 8) = o;
    }
}

// ---------------- hg = x3 @ Wg  (N,256)@(256,16), bf16 x3 --------------
__global__ __launch_bounds__(256) void k_hg(const ushort_t* __restrict__ x3bf,
                                            const float* __restrict__ Wg,
                                            float* __restrict__ hg) {
    __shared__ float xs[16 * HC2];
    int n0 = blockIdx.x * 16;
    int t  = threadIdx.x;
    for (int q = t; q < 16 * HC2 / 4; q += 256) {
        int r  = q >> 6;           // row within tile (64 ushort4 per row)
        int cc = (q & 63) * 4;
        int n  = n0 + r;
        ushort4 v = make_ushort4(0, 0, 0, 0);
        if (n < N_NODES) v = *(const ushort4*)(x3bf + (size_t)n * HC2 + cc);
        xs[r * HC2 + cc + 0] = bf2f(v.x);
        xs[r * HC2 + cc + 1] = bf2f(v.y);
        xs[r * HC2 + cc + 2] = bf2f(v.z);
        xs[r * HC2 + cc + 3] = bf2f(v.w);
    }
    __syncthreads();
    int r = t >> 4, c = t & 15;
    float acc = 0.f;
#pragma unroll 4
    for (int k = 0; k < HC2; k++) acc += xs[r * HC2 + k] * Wg[k * C3 + c];
    int n = n0 + r;
    if (n < N_NODES) hg[(size_t)n * C3 + c] = acc;
}

// ---------------- GCN aggregate + ELU + FC + sigmoid (fused) -----------
__global__ __launch_bounds__(256) void k_gcn_out(const float* __restrict__ hg,
                                                 const float* __restrict__ ew,
                                                 const float* __restrict__ degf,
                                                 const int* __restrict__ offs,
                                                 const int2* __restrict__ csr,
                                                 const float* __restrict__ bg,
                                                 const float* __restrict__ Wfc,
                                                 const float* __restrict__ bfc,
                                                 float* __restrict__ out) {
    int t = threadIdx.x;
    int r = t >> 4, c = t & 15;
    int d = blockIdx.x * 16 + r;
    float val = 0.f;
    if (d < N_NODES) {
        float dd = degf[d];
        float dinv_d = dd > 0.f ? rsqrtf(dd) : 0.f;
        int k0 = offs[d], k1 = offs[d + 1];
        float acc = 0.f;
        for (int k = k0; k < k1; k++) {
            int2 se = csr[k];
            float w = (se.y < N_EDGES) ? ew[se.y] : 1.f;
            float ds_ = degf[se.x];
            float dinv_s = ds_ > 0.f ? rsqrtf(ds_) : 0.f;
            acc += hg[(size_t)se.x * C3 + c] * (dinv_s * w * dinv_d);
        }
        val = eluf(acc + bg[c]);
    }
    float z = val * Wfc[c];
#pragma unroll
    for (int off = 8; off >= 1; off >>= 1) z += __shfl_xor(z, off, 16);
    if (c == 0 && d < N_NODES) out[d] = 1.f / (1.f + expf(-(z + bfc[0])));
}

// =======================================================================
extern "C" void kernel_launch(void* const* d_in, const int* in_sizes, int n_in,
                              void* d_out, int out_size, void* d_ws, size_t ws_size,
                              hipStream_t stream) {
    const float* x       = (const float*)d_in[0];
    const int*   ei      = (const int*)  d_in[1];
    const float* ew      = (const float*)d_in[2];
    const float* W1      = (const float*)d_in[3];
    const float* a_src1  = (const float*)d_in[4];
    const float* a_dst1  = (const float*)d_in[5];
    const float* b1      = (const float*)d_in[6];
    const float* W2      = (const float*)d_in[7];
    const float* a_src2  = (const float*)d_in[8];
    const float* a_dst2  = (const float*)d_in[9];
    const float* b2      = (const float*)d_in[10];
    const float* Wg      = (const float*)d_in[11];
    const float* bg      = (const float*)d_in[12];
    const float* Wfc     = (const float*)d_in[13];
    const float* bfc     = (const float*)d_in[14];
    float* out = (float*)d_out;

    char* w = (char*)d_ws;
    size_t off = 0;
    auto alloc = [&](size_t bytes) -> void* {
        void* p = w + off;
        off = (off + bytes + 255) & ~(size_t)255;
        return p;
    };
    ushort_t* x2bf = (ushort_t*)alloc((size_t)MPAD * HC1 * 2);
    ushort_t* W2X  = (ushort_t*)alloc((size_t)GCOLS * HC1 * 2);
    ushort_t* h2bf = (ushort_t*)alloc((size_t)N_NODES * HC2 * 2);
    ushort_t* x3bf = (ushort_t*)alloc((size_t)N_NODES * HC2 * 2);
    float* hg     = (float*)alloc((size_t)N_NODES * C3 * 4);
    float* aggx   = (float*)alloc((size_t)F_IN * NH8 * 4);
    float* es1    = (float*)alloc((size_t)NH8 * 4);
    float* ed1    = (float*)alloc((size_t)NH8 * 4);
    float* es2    = (float*)alloc((size_t)NH8 * 4);
    float* ed2    = (float*)alloc((size_t)NH8 * 4);
    float* as1f   = (float*)alloc((size_t)HEADS * F_IN * 4);
    float* ad1f   = (float*)alloc((size_t)HEADS * F_IN * 4);
    // keep the three zero-init buffers contiguous: one async memset covers them
    float* degf   = (float*)alloc((size_t)N_NODES * 4);
    int*   degi   = (int*)  alloc((size_t)N_NODES * 4);
    int*   cursor = (int*)  alloc((size_t)N_NODES * 4);
    char*  zero_end = w + off;
    int*   offs   = (int*)  alloc((size_t)(N_NODES + 1) * 4);
    int*   part   = (int*)  alloc(256 * 4);
    int2*  csr    = (int2*) alloc((size_t)ETOT * 8);

    const int T = 256;
    // ---- CSR build + init + weight prep ----
    hipMemsetAsync(degf, 0, (size_t)(zero_end - (char*)degf), stream);
    k_deg<<<dim3((ETOT + T - 1) / T), dim3(T), 0, stream>>>(ei, ew, degi, degf);
    k_scan_a<<<dim3(NCHUNK), dim3(256), 0, stream>>>(degi, part);
    k_scan_b<<<dim3(1), dim3(256), 0, stream>>>(part);
    k_scan_c<<<dim3(NCHUNK), dim3(256), 0, stream>>>(degi, part, offs);
    k_prep<<<dim3(PACKBLK + 1), dim3(256), 0, stream>>>(
        W2, a_src2, a_dst2, W2X, W1, a_src1, a_dst1, as1f, ad1f);
    k_scatter_es1<<<dim3(SCATBLK + ES1BLK), dim3(256), 0, stream>>>(
        ei, offs, cursor, csr, x, as1f, ad1f, es1, ed1);

    // ---- GAT layer 1 (linearity trick; exp inline in agg) ----
    k_agg_x<<<dim3((NH8 + T - 1) / T), dim3(T), 0, stream>>>(x, es1, ed1, offs, csr, aggx);
    k_expand<<<dim3((N_NODES + 3) / 4), dim3(256), 0, stream>>>(aggx, W1, b1, x2bf);

    // ---- GAT layer 2 (GEMM emits es2/ed2; exp inline in agg) ----
    k_gemm_mfma<<<dim3(MPAD / 64), dim3(256), 0, stream>>>(
        (const short*)x2bf, (const short*)W2X, h2bf, es2, ed2);
    k_gat_agg2<<<dim3((N_NODES + 3) / 4), dim3(256), 0, stream>>>(
        h2bf, es2, ed2, offs, csr, b2, x3bf);

    // ---- GCN + FC + sigmoid ----
    k_hg<<<dim3((N_NODES + 15) / 16), dim3(256), 0, stream>>>(x3bf, Wg, hg);
    k_gcn_out<<<dim3((N_NODES + 15) / 16), dim3(256), 0, stream>>>(
        hg, ew, degf, offs, csr, bg, Wfc, bfc, out);
}

// Round 16
// 326.087 us; speedup vs baseline: 1.0224x; 1.0224x over previous
//
#include <hip/hip_runtime.h>
#include <hip/hip_bf16.h>
#include <float.h>
#include <math.h>

#define N_NODES 50000
#define N_EDGES 400000
#define ETOT    (N_EDGES + N_NODES)   // 450000
#define F_IN    5
#define HEADS   8
#define C1      64
#define C2      32
#define C3      16
#define HC1     (HEADS * C1)          // 512
#define HC2     (HEADS * C2)          // 256
#define NEG_SLOPE 0.2f
#define NCHUNK  ((N_NODES + 255) / 256)  // 196
#define NH8     (N_NODES * HEADS)        // 400000
#define MPAD    (((N_NODES + 63) / 64) * 64)  // 50048 rows for MFMA GEMM
#define GCOLS   (HC2 + 16)            // 272: 256 h2 cols + 8 es + 8 ed
#define PACKBLK ((GCOLS * HC1) / 256) // 544 blocks for packW2X part
#define SCATBLK ((ETOT + 255) / 256)  // 1758 blocks for scatter part
#define ES1BLK  ((NH8 + 255) / 256)   // 1563 blocks for es1 part

typedef short bf16x8 __attribute__((ext_vector_type(8)));
typedef float f32x4  __attribute__((ext_vector_type(4)));
typedef unsigned short ushort_t;
typedef unsigned short ushort8_t __attribute__((ext_vector_type(8)));

__device__ __forceinline__ float eluf(float x) {
    return x > 0.f ? x : (expf(x) - 1.f);
}
__device__ __forceinline__ float bf2f(unsigned short u) {
    union { unsigned int i; float f; } v; v.i = ((unsigned int)u) << 16; return v.f;
}
__device__ __forceinline__ unsigned short f2bf(float f) {
    __hip_bfloat16 b = __float2bfloat16(f);
    return *(unsigned short*)&b;
}
__device__ __forceinline__ float softnum(float es, float ed) {
    float v = es + ed;
    v = v > 0.f ? v : NEG_SLOPE * v;
    return expf(v);
}

// ---------------- degree histogram (int count + weighted for GCN) ------
__global__ void k_deg(const int* __restrict__ ei, const float* __restrict__ ew,
                      int* degi, float* degf) {
    int i = blockIdx.x * blockDim.x + threadIdx.x;
    if (i >= ETOT) return;
    int d   = (i < N_EDGES) ? ei[N_EDGES + i] : (i - N_EDGES);
    float w = (i < N_EDGES) ? ew[i] : 1.f;
    atomicAdd(&degi[d], 1);
    atomicAdd(&degf[d], w);
}

// ---------------- 3-kernel exclusive scan over deg[N] ------------------
__global__ void k_scan_a(const int* __restrict__ deg, int* __restrict__ part) {
    __shared__ int lds[256];
    int t = threadIdx.x;
    int i = blockIdx.x * 256 + t;
    lds[t] = (i < N_NODES) ? deg[i] : 0;
    __syncthreads();
    for (int off = 128; off >= 1; off >>= 1) {
        if (t < off) lds[t] += lds[t + off];
        __syncthreads();
    }
    if (t == 0) part[blockIdx.x] = lds[0];
}

__global__ void k_scan_b(int* part) {
    __shared__ int lds[256];
    int t = threadIdx.x;
    int v = (t < NCHUNK) ? part[t] : 0;
    lds[t] = v;
    __syncthreads();
    for (int off = 1; off < 256; off <<= 1) {
        int x = (t >= off) ? lds[t - off] : 0;
        __syncthreads();
        lds[t] += x;
        __syncthreads();
    }
    if (t < NCHUNK) part[t] = lds[t] - v;
}

__global__ void k_scan_c(const int* __restrict__ deg, const int* __restrict__ part,
                         int* __restrict__ offs) {
    __shared__ int lds[256];
    int t = threadIdx.x;
    int i = blockIdx.x * 256 + t;
    int v = (i < N_NODES) ? deg[i] : 0;
    lds[t] = v;
    __syncthreads();
    for (int off = 1; off < 256; off <<= 1) {
        int x = (t >= off) ? lds[t - off] : 0;
        __syncthreads();
        lds[t] += x;
        __syncthreads();
    }
    int excl = part[blockIdx.x] + lds[t] - v;
    if (i < N_NODES) offs[i] = excl;
    if (i == N_NODES - 1) offs[N_NODES] = excl + v;
}

// -------- merged weight prep: packW2X (blocks 0..543) + fold (block 544)
__global__ void k_prep(const float* __restrict__ W2,
                       const float* __restrict__ a_src2, const float* __restrict__ a_dst2,
                       ushort_t* __restrict__ W2X,
                       const float* __restrict__ W1,
                       const float* __restrict__ a_src1, const float* __restrict__ a_dst1,
                       float* __restrict__ as1f, float* __restrict__ ad1f) {
    if (blockIdx.x < PACKBLK) {
        int idx = blockIdx.x * 256 + threadIdx.x;
        int c = idx >> 9;       // output column 0..271
        int k = idx & 511;      // k index
        float v;
        if (c < HC2) {
            v = W2[(size_t)k * HC2 + c];
        } else {
            int h = (c - HC2) & 7;
            const float* av = (c < HC2 + 8) ? a_src2 : a_dst2;
            v = 0.f;
#pragma unroll 8
            for (int j = 0; j < C2; j++)
                v += W2[(size_t)k * HC2 + h * C2 + j] * av[h * C2 + j];
        }
        W2X[idx] = f2bf(v);
    } else {
        int idx = threadIdx.x;
        if (idx >= HEADS * F_IN) return;
        int h = idx / F_IN, f = idx % F_IN;
        float s = 0.f, d = 0.f;
        for (int c = 0; c < C1; c++) {
            float w = W1[f * HC1 + h * C1 + c];
            s += w * a_src1[h * C1 + c];
            d += w * a_dst1[h * C1 + c];
        }
        as1f[idx] = s;
        ad1f[idx] = d;
    }
}

// -------- merged: scatter CSR (blocks 0..1757) + es1/ed1 (rest) --------
__global__ void k_scatter_es1(const int* __restrict__ ei, const int* __restrict__ offs,
                              int* cursor, int2* __restrict__ csr,
                              const float* __restrict__ x,
                              const float* __restrict__ as1f, const float* __restrict__ ad1f,
                              float* __restrict__ es, float* __restrict__ ed) {
    if (blockIdx.x < SCATBLK) {
        int i = blockIdx.x * 256 + threadIdx.x;
        if (i >= ETOT) return;
        int s, d;
        if (i < N_EDGES) { s = ei[i]; d = ei[N_EDGES + i]; }
        else             { s = d = i - N_EDGES; }
        int pos = offs[d] + atomicAdd(&cursor[d], 1);
        csr[pos] = make_int2(s, i);
    } else {
        int g = (blockIdx.x - SCATBLK) * 256 + threadIdx.x;
        if (g >= NH8) return;
        int n = g >> 3, h = g & 7;
        float vs = 0.f, vd = 0.f;
#pragma unroll
        for (int f = 0; f < F_IN; f++) {
            float xv = x[n * F_IN + f];
            vs += xv * as1f[h * F_IN + f];
            vd += xv * ad1f[h * F_IN + f];
        }
        es[g] = vs;
        ed[g] = vd;
    }
}

// -------- layer-1 aggregation, exp inline, csr software-pipelined ------
__global__ void k_agg_x(const float* __restrict__ x,
                        const float* __restrict__ es1, const float* __restrict__ ed1,
                        const int* __restrict__ offs, const int2* __restrict__ csr,
                        float* __restrict__ aggx) {
    int g = blockIdx.x * blockDim.x + threadIdx.x;
    if (g >= NH8) return;
    int d = g >> 3, h = g & 7;
    float edv = ed1[g];
    int k0 = offs[d], k1 = offs[d + 1];
    float a0 = 0.f, a1 = 0.f, a2 = 0.f, a3 = 0.f, a4 = 0.f, exsum = 0.f;
    int k = k0;
    if (k + 1 < k1) {
        int2 c0 = csr[k], c1 = csr[k + 1];
        for (; k + 3 < k1; k += 2) {
            int2 n0 = csr[k + 2], n1 = csr[k + 3];   // prefetch next pair
            float x0 = softnum(es1[c0.x * HEADS + h], edv);
            float x1 = softnum(es1[c1.x * HEADS + h], edv);
            const float* xp0 = x + c0.x * F_IN;
            const float* xp1 = x + c1.x * F_IN;
            a0 += x0 * xp0[0] + x1 * xp1[0];
            a1 += x0 * xp0[1] + x1 * xp1[1];
            a2 += x0 * xp0[2] + x1 * xp1[2];
            a3 += x0 * xp0[3] + x1 * xp1[3];
            a4 += x0 * xp0[4] + x1 * xp1[4];
            exsum += x0 + x1;
            c0 = n0; c1 = n1;
        }
        {
            float x0 = softnum(es1[c0.x * HEADS + h], edv);
            float x1 = softnum(es1[c1.x * HEADS + h], edv);
            const float* xp0 = x + c0.x * F_IN;
            const float* xp1 = x + c1.x * F_IN;
            a0 += x0 * xp0[0] + x1 * xp1[0];
            a1 += x0 * xp0[1] + x1 * xp1[1];
            a2 += x0 * xp0[2] + x1 * xp1[2];
            a3 += x0 * xp0[3] + x1 * xp1[3];
            a4 += x0 * xp0[4] + x1 * xp1[4];
            exsum += x0 + x1;
            k += 2;
        }
    }
    if (k < k1) {
        int2 c0 = csr[k];
        float x0 = softnum(es1[c0.x * HEADS + h], edv);
        const float* xp0 = x + c0.x * F_IN;
        a0 += x0 * xp0[0];
        a1 += x0 * xp0[1];
        a2 += x0 * xp0[2];
        a3 += x0 * xp0[3];
        a4 += x0 * xp0[4];
        exsum += x0;
    }
    float inv = 1.f / (exsum + 1e-16f);
    aggx[0 * NH8 + g] = a0 * inv;
    aggx[1 * NH8 + g] = a1 * inv;
    aggx[2 * NH8 + g] = a2 * inv;
    aggx[3 * NH8 + g] = a3 * inv;
    aggx[4 * NH8 + g] = a4 * inv;
}

// -------- expand aggx (N,8,5) @ W1 -> x2 = elu(. + b1), store bf16 -----
// One wave per node: lane j owns channels [j*8, j*8+8). No cross-lane ops.
__global__ __launch_bounds__(256) void k_expand(const float* __restrict__ aggx,
                                                const float* __restrict__ W1,
                                                const float* __restrict__ b1,
                                                ushort_t* __restrict__ x2bf) {
    int wave = threadIdx.x >> 6;          // 0..3
    int j    = threadIdx.x & 63;
    int n    = blockIdx.x * 4 + wave;
    if (n >= N_NODES) return;
    int h = j >> 3;                        // head of this channel slice
    int g = n * HEADS + h;
    float av[F_IN];
#pragma unroll
    for (int f = 0; f < F_IN; f++) av[f] = aggx[f * NH8 + g];

    const float* w1p = W1 + j * 8;         // hc = j*8 = h*64 + (j&7)*8
    float4 s0 = *(const float4*)(b1 + j * 8);
    float4 s1 = *(const float4*)(b1 + j * 8 + 4);
#pragma unroll
    for (int f = 0; f < F_IN; f++) {
        float4 w0  = *(const float4*)(w1p + f * HC1);
        float4 w1v = *(const float4*)(w1p + f * HC1 + 4);
        s0.x += av[f] * w0.x;  s0.y += av[f] * w0.y;
        s0.z += av[f] * w0.z;  s0.w += av[f] * w0.w;
        s1.x += av[f] * w1v.x; s1.y += av[f] * w1v.y;
        s1.z += av[f] * w1v.z; s1.w += av[f] * w1v.w;
    }
    ushort8_t o;
    o[0] = f2bf(eluf(s0.x)); o[1] = f2bf(eluf(s0.y));
    o[2] = f2bf(eluf(s0.z)); o[3] = f2bf(eluf(s0.w));
    o[4] = f2bf(eluf(s1.x)); o[5] = f2bf(eluf(s1.y));
    o[6] = f2bf(eluf(s1.z)); o[7] = f2bf(eluf(s1.w));
    *(ushort8_t*)(x2bf + (size_t)n * HC1 + j * 8) = o;
}

// ------ bf16 MFMA GEMM: round-10 version (16 rows/wave, 256 thr) -------
// LDS-staged B + XOR swizzle + reg prefetch. Known-good.
__global__ __launch_bounds__(256, 3) void k_gemm_mfma(const short* __restrict__ A,
                                                      const short* __restrict__ W2X,
                                                      ushort_t* __restrict__ h2bf,
                                                      float* __restrict__ es2,
                                                      float* __restrict__ ed2) {
    __shared__ short Bs[GCOLS * 32];   // 272 cols * 64 B = 17408 B
    int t    = threadIdx.x;
    int wave = t >> 6;
    int lane = t & 63;
    int lo   = lane & 15;
    int quad = lane >> 4;
    int m0   = blockIdx.x * 64 + wave * 16;
    const short* ap = A + (size_t)(m0 + lo) * HC1 + quad * 8;

    f32x4 acc[17];
#pragma unroll
    for (int f = 0; f < 17; f++) acc[f] = (f32x4){0.f, 0.f, 0.f, 0.f};

    // stage tile k0=0
    for (int idx = t; idx < GCOLS * 4; idx += 256) {
        int c = idx >> 2, q = idx & 3;
        int s = (q + c + (c >> 2)) & 3;
        *(bf16x8*)(Bs + c * 32 + s * 8) = *(const bf16x8*)(W2X + (size_t)c * HC1 + q * 8);
    }
    __syncthreads();

#pragma unroll 1
    for (int k0 = 0; k0 < HC1; k0 += 32) {
        int nk = k0 + 32;
        bf16x8 pre[5];
        if (nk < HC1) {
#pragma unroll
            for (int j = 0; j < 5; j++) {
                int idx = t + j * 256;
                if (idx < GCOLS * 4) {
                    int c = idx >> 2, q = idx & 3;
                    pre[j] = *(const bf16x8*)(W2X + (size_t)c * HC1 + nk + q * 8);
                }
            }
        }
        bf16x8 aF = *(const bf16x8*)(ap + k0);
#pragma unroll
        for (int f = 0; f < 17; f++) {
            int c = f * 16 + lo;
            int s = (quad + c + (c >> 2)) & 3;
            bf16x8 bF = *(const bf16x8*)(Bs + c * 32 + s * 8);
            acc[f] = __builtin_amdgcn_mfma_f32_16x16x32_bf16(aF, bF, acc[f], 0, 0, 0);
        }
        __syncthreads();
        if (nk < HC1) {
#pragma unroll
            for (int j = 0; j < 5; j++) {
                int idx = t + j * 256;
                if (idx < GCOLS * 4) {
                    int c = idx >> 2, q = idx & 3;
                    int s = (q + c + (c >> 2)) & 3;
                    *(bf16x8*)(Bs + c * 32 + s * 8) = pre[j];
                }
            }
            __syncthreads();
        }
    }

    int rowb = m0 + quad * 4;
#pragma unroll
    for (int f = 0; f < 16; f++) {
#pragma unroll
        for (int r = 0; r < 4; r++) {
            int row = rowb + r;
            if (row < N_NODES)
                h2bf[(size_t)row * HC2 + f * 16 + lo] = f2bf(acc[f][r]);
        }
    }
#pragma unroll
    for (int r = 0; r < 4; r++) {
        int row = rowb + r;
        if (row < N_NODES) {
            if (lo < 8) es2[row * HEADS + lo]       = acc[16][r];
            else        ed2[row * HEADS + (lo - 8)] = acc[16][r];
        }
    }
}

// -------- layer-2 GAT agg: wave per dst, exp inline, csr pipelined -----
// Empirical optimum for this gather (R12-R15 A/B): 4 lanes/row, 8B loads,
// 2 independent edges in flight. Dual-edge 16B lanes (R15) and hg fusion
// (R13) both regressed.
__global__ __launch_bounds__(256) void k_gat_agg2(const ushort_t* __restrict__ h2bf,
                                                  const float* __restrict__ es2,
                                                  const float* __restrict__ ed2,
                                                  const int* __restrict__ offs,
                                                  const int2* __restrict__ csr,
                                                  const float* __restrict__ b2,
                                                  ushort_t* __restrict__ x3bf) {
    int wave = threadIdx.x >> 6;
    int lane = threadIdx.x & 63;
    int d = blockIdx.x * 4 + wave;
    if (d >= N_NODES) return;
    int c4 = lane * 4;            // 4 channels per lane
    int h  = lane >> 3;           // head = c4/32
    float edv = ed2[d * HEADS + h];
    int k0 = offs[d], k1 = offs[d + 1];
    float acc0 = 0.f, acc1 = 0.f, acc2 = 0.f, acc3 = 0.f, exsum = 0.f;
    int k = k0;
    if (k + 1 < k1) {
        int2 e0 = csr[k], e1 = csr[k + 1];
        for (; k + 3 < k1; k += 2) {
            int2 n0 = csr[k + 2], n1 = csr[k + 3];   // prefetch next pair
            float x0 = softnum(es2[e0.x * HEADS + h], edv);
            float x1 = softnum(es2[e1.x * HEADS + h], edv);
            ushort4 v0 = *(const ushort4*)(h2bf + (size_t)e0.x * HC2 + c4);
            ushort4 v1 = *(const ushort4*)(h2bf + (size_t)e1.x * HC2 + c4);
            acc0 += x0 * bf2f(v0.x) + x1 * bf2f(v1.x);
            acc1 += x0 * bf2f(v0.y) + x1 * bf2f(v1.y);
            acc2 += x0 * bf2f(v0.z) + x1 * bf2f(v1.z);
            acc3 += x0 * bf2f(v0.w) + x1 * bf2f(v1.w);
            exsum += x0 + x1;
            e0 = n0; e1 = n1;
        }
        {
            float x0 = softnum(es2[e0.x * HEADS + h], edv);
            float x1 = softnum(es2[e1.x * HEADS + h], edv);
            ushort4 v0 = *(const ushort4*)(h2bf + (size_t)e0.x * HC2 + c4);
            ushort4 v1 = *(const ushort4*)(h2bf + (size_t)e1.x * HC2 + c4);
            acc0 += x0 * bf2f(v0.x) + x1 * bf2f(v1.x);
            acc1 += x0 * bf2f(v0.y) + x1 * bf2f(v1.y);
            acc2 += x0 * bf2f(v0.z) + x1 * bf2f(v1.z);
            acc3 += x0 * bf2f(v0.w) + x1 * bf2f(v1.w);
            exsum += x0 + x1;
            k += 2;
        }
    }
    if (k < k1) {
        int2 e0 = csr[k];
        float x0 = softnum(es2[e0.x * HEADS + h], edv);
        ushort4 v0 = *(const ushort4*)(h2bf + (size_t)e0.x * HC2 + c4);
        acc0 += x0 * bf2f(v0.x);
        acc1 += x0 * bf2f(v0.y);
        acc2 += x0 * bf2f(v0.z);
        acc3 += x0 * bf2f(v0.w);
        exsum += x0;
    }
    float inv = 1.f / (exsum + 1e-16f);
    float4 bias = *(const float4*)(b2 + c4);
    ushort4 o;
    o.x = f2bf(eluf(acc0 * inv + bias.x));
    o.y = f2bf(eluf(acc1 * inv + bias.y));
    o.z = f2bf(eluf(acc2 * inv + bias.z));
    o.w = f2bf(eluf(acc3 * inv + bias.w));
    *(ushort4*)(x3bf + (size_t)d * HC2 + c4) = o;
}

// ---------------- hg = x3 @ Wg  (N,256)@(256,16), bf16 x3 --------------
__global__ __launch_bounds__(256) void k_hg(const ushort_t* __restrict__ x3bf,
                                            const float* __restrict__ Wg,
                                            float* __restrict__ hg) {
    __shared__ float xs[16 * HC2];
    int n0 = blockIdx.x * 16;
    int t  = threadIdx.x;
    for (int q = t; q < 16 * HC2 / 4; q += 256) {
        int r  = q >> 6;           // row within tile (64 ushort4 per row)
        int cc = (q & 63) * 4;
        int n  = n0 + r;
        ushort4 v = make_ushort4(0, 0, 0, 0);
        if (n < N_NODES) v = *(const ushort4*)(x3bf + (size_t)n * HC2 + cc);
        xs[r * HC2 + cc + 0] = bf2f(v.x);
        xs[r * HC2 + cc + 1] = bf2f(v.y);
        xs[r * HC2 + cc + 2] = bf2f(v.z);
        xs[r * HC2 + cc + 3] = bf2f(v.w);
    }
    __syncthreads();
    int r = t >> 4, c = t & 15;
    float acc = 0.f;
#pragma unroll 4
    for (int k = 0; k < HC2; k++) acc += xs[r * HC2 + k] * Wg[k * C3 + c];
    int n = n0 + r;
    if (n < N_NODES) hg[(size_t)n * C3 + c] = acc;
}

// ---------------- GCN aggregate + ELU + FC + sigmoid (fused) -----------
__global__ __launch_bounds__(256) void k_gcn_out(const float* __restrict__ hg,
                                                 const float* __restrict__ ew,
                                                 const float* __restrict__ degf,
                                                 const int* __restrict__ offs,
                                                 const int2* __restrict__ csr,
                                                 const float* __restrict__ bg,
                                                 const float* __restrict__ Wfc,
                                                 const float* __restrict__ bfc,
                                                 float* __restrict__ out) {
    int t = threadIdx.x;
    int r = t >> 4, c = t & 15;
    int d = blockIdx.x * 16 + r;
    float val = 0.f;
    if (d < N_NODES) {
        float dd = degf[d];
        float dinv_d = dd > 0.f ? rsqrtf(dd) : 0.f;
        int k0 = offs[d], k1 = offs[d + 1];
        float acc = 0.f;
        for (int k = k0; k < k1; k++) {
            int2 se = csr[k];
            float w = (se.y < N_EDGES) ? ew[se.y] : 1.f;
            float ds_ = degf[se.x];
            float dinv_s = ds_ > 0.f ? rsqrtf(ds_) : 0.f;
            acc += hg[(size_t)se.x * C3 + c] * (dinv_s * w * dinv_d);
        }
        val = eluf(acc + bg[c]);
    }
    float z = val * Wfc[c];
#pragma unroll
    for (int off = 8; off >= 1; off >>= 1) z += __shfl_xor(z, off, 16);
    if (c == 0 && d < N_NODES) out[d] = 1.f / (1.f + expf(-(z + bfc[0])));
}

// =======================================================================
extern "C" void kernel_launch(void* const* d_in, const int* in_sizes, int n_in,
                              void* d_out, int out_size, void* d_ws, size_t ws_size,
                              hipStream_t stream) {
    const float* x       = (const float*)d_in[0];
    const int*   ei      = (const int*)  d_in[1];
    const float* ew      = (const float*)d_in[2];
    const float* W1      = (const float*)d_in[3];
    const float* a_src1  = (const float*)d_in[4];
    const float* a_dst1  = (const float*)d_in[5];
    const float* b1      = (const float*)d_in[6];
    const float* W2      = (const float*)d_in[7];
    const float* a_src2  = (const float*)d_in[8];
    const float* a_dst2  = (const float*)d_in[9];
    const float* b2      = (const float*)d_in[10];
    const float* Wg      = (const float*)d_in[11];
    const float* bg      = (const float*)d_in[12];
    const float* Wfc     = (const float*)d_in[13];
    const float* bfc     = (const float*)d_in[14];
    float* out = (float*)d_out;

    char* w = (char*)d_ws;
    size_t off = 0;
    auto alloc = [&](size_t bytes) -> void* {
        void* p = w + off;
        off = (off + bytes + 255) & ~(size_t)255;
        return p;
    };
    ushort_t* x2bf = (ushort_t*)alloc((size_t)MPAD * HC1 * 2);
    ushort_t* W2X  = (ushort_t*)alloc((size_t)GCOLS * HC1 * 2);
    ushort_t* h2bf = (ushort_t*)alloc((size_t)N_NODES * HC2 * 2);
    ushort_t* x3bf = (ushort_t*)alloc((size_t)N_NODES * HC2 * 2);
    float* hg     = (float*)alloc((size_t)N_NODES * C3 * 4);
    float* aggx   = (float*)alloc((size_t)F_IN * NH8 * 4);
    float* es1    = (float*)alloc((size_t)NH8 * 4);
    float* ed1    = (float*)alloc((size_t)NH8 * 4);
    float* es2    = (float*)alloc((size_t)NH8 * 4);
    float* ed2    = (float*)alloc((size_t)NH8 * 4);
    float* as1f   = (float*)alloc((size_t)HEADS * F_IN * 4);
    float* ad1f   = (float*)alloc((size_t)HEADS * F_IN * 4);
    // keep the three zero-init buffers contiguous: one async memset covers them
    float* degf   = (float*)alloc((size_t)N_NODES * 4);
    int*   degi   = (int*)  alloc((size_t)N_NODES * 4);
    int*   cursor = (int*)  alloc((size_t)N_NODES * 4);
    char*  zero_end = w + off;
    int*   offs   = (int*)  alloc((size_t)(N_NODES + 1) * 4);
    int*   part   = (int*)  alloc(256 * 4);
    int2*  csr    = (int2*) alloc((size_t)ETOT * 8);

    const int T = 256;
    // ---- CSR build + init + weight prep ----
    hipMemsetAsync(degf, 0, (size_t)(zero_end - (char*)degf), stream);
    k_deg<<<dim3((ETOT + T - 1) / T), dim3(T), 0, stream>>>(ei, ew, degi, degf);
    k_scan_a<<<dim3(NCHUNK), dim3(256), 0, stream>>>(degi, part);
    k_scan_b<<<dim3(1), dim3(256), 0, stream>>>(part);
    k_scan_c<<<dim3(NCHUNK), dim3(256), 0, stream>>>(degi, part, offs);
    k_prep<<<dim3(PACKBLK + 1), dim3(256), 0, stream>>>(
        W2, a_src2, a_dst2, W2X, W1, a_src1, a_dst1, as1f, ad1f);
    k_scatter_es1<<<dim3(SCATBLK + ES1BLK), dim3(256), 0, stream>>>(
        ei, offs, cursor, csr, x, as1f, ad1f, es1, ed1);

    // ---- GAT layer 1 (linearity trick; exp inline in agg) ----
    k_agg_x<<<dim3((NH8 + T - 1) / T), dim3(T), 0, stream>>>(x, es1, ed1, offs, csr, aggx);
    k_expand<<<dim3((N_NODES + 3) / 4), dim3(256), 0, stream>>>(aggx, W1, b1, x2bf);

    // ---- GAT layer 2 (GEMM emits es2/ed2; exp inline in agg) ----
    k_gemm_mfma<<<dim3(MPAD / 64), dim3(256), 0, stream>>>(
        (const short*)x2bf, (const short*)W2X, h2bf, es2, ed2);
    k_gat_agg2<<<dim3((N_NODES + 3) / 4), dim3(256), 0, stream>>>(
        h2bf, es2, ed2, offs, csr, b2, x3bf);

    // ---- GCN + FC + sigmoid ----
    k_hg<<<dim3((N_NODES + 15) / 16), dim3(256), 0, stream>>>(x3bf, Wg, hg);
    k_gcn_out<<<dim3((N_NODES + 15) / 16), dim3(256), 0, stream>>>(
        hg, ew, degf, offs, csr, bg, Wfc, bfc, out);
}